// Round 10
// baseline (259.898 us; speedup 1.0000x reference)
//
#include <hip/hip_runtime.h>
#include <hip/hip_bf16.h>

// Problem dims
#define BN 16384
#define FN 256
#define RN 32
#define CN 16
#define H1N 128
#define H2N 32
#define G1N 256
#define G2N 64

typedef __bf16 bf16_t;
typedef __bf16 bf16x8 __attribute__((ext_vector_type(8)));
typedef __bf16 bf16x4 __attribute__((ext_vector_type(4)));
typedef float f32x4 __attribute__((ext_vector_type(4)));

// ---- workspace byte offsets (all 16B-aligned) ----
#define OFF_DATA   0UL
#define OFF_WF1    8388608UL
#define OFF_WF2    8454144UL
#define OFF_WC1    8462336UL
#define OFF_WC2    12656640UL
#define OFF_WC3    13705216UL
#define OFF_FSINI  13770752UL
#define OFF_C3     15867904UL

__device__ __forceinline__ f32x4 mfma16(bf16x8 a, bf16x8 b, f32x4 c) {
  return __builtin_amdgcn_mfma_f32_16x16x32_bf16(a, b, c, 0, 0, 0);
}

__device__ __forceinline__ float elu_f(float v) {
  float e = __builtin_amdgcn_exp2f(v * 1.44269504f) - 1.0f;
  return v > 0.f ? v : e;
}

__device__ __forceinline__ bf16x8 lfrag(const char* base, int strideB, int n0, int k0, int lane) {
  int row = n0 + (lane & 15);
  int off = (k0 * 2 + ((lane >> 4) << 4)) ^ ((row & 7) << 4);
  return *(const bf16x8*)(base + row * strideB + off);
}

__device__ __forceinline__ void pack_frag8(const float* __restrict__ src, bf16_t* __restrict__ dst,
                                           int NT, int KS, int g) {
  int per = NT * KS * 64;
  int r = g / per;
  int local = g - r * per;
  int lane = local & 63;
  int fr = local >> 6;
  int ks = fr / NT;
  int nt = fr - ks * NT;
  int N = NT * 16, K = KS * 32;
  int n = nt * 16 + (lane & 15);
  int k = ks * 32 + ((lane >> 4) << 3);
  const float* s = src + (long)r * N * K + (long)n * K + k;
  float4 a = *(const float4*)s;
  float4 b = *(const float4*)(s + 4);
  bf16x8 o;
  o[0] = (bf16_t)a.x; o[1] = (bf16_t)a.y; o[2] = (bf16_t)a.z; o[3] = (bf16_t)a.w;
  o[4] = (bf16_t)b.x; o[5] = (bf16_t)b.y; o[6] = (bf16_t)b.z; o[7] = (bf16_t)b.w;
  *(bf16x8*)(dst + (long)g * 8) = o;
}

#define G_DATA 524288
#define G_WC1  262144
#define G_WC2  65536
#define G_WF1  4096
#define G_WC3  4096
#define G_WF2  512
#define G_TOTAL (G_DATA + G_WC1 + G_WC2 + G_WF1 + G_WC3 + G_WF2)

__global__ __launch_bounds__(256) void k0_pack(
    const float* __restrict__ data, const float* __restrict__ Wf1, const float* __restrict__ Wf2,
    const float* __restrict__ Wc1, const float* __restrict__ Wc2, const float* __restrict__ Wc3,
    char* __restrict__ ws)
{
  int g = blockIdx.x * 256 + threadIdx.x;
  if (g < G_DATA) {
    const float* s = data + (long)g * 8;
    float4 a = *(const float4*)s, b = *(const float4*)(s + 4);
    bf16x8 o;
    o[0] = (bf16_t)a.x; o[1] = (bf16_t)a.y; o[2] = (bf16_t)a.z; o[3] = (bf16_t)a.w;
    o[4] = (bf16_t)b.x; o[5] = (bf16_t)b.y; o[6] = (bf16_t)b.z; o[7] = (bf16_t)b.w;
    *(bf16x8*)((bf16_t*)(ws + OFF_DATA) + (long)g * 8) = o;
    return;
  }
  g -= G_DATA;
  if (g < G_WC1) { pack_frag8(Wc1, (bf16_t*)(ws + OFF_WC1), 16, 8, g); return; }
  g -= G_WC1;
  if (g < G_WC2) { pack_frag8(Wc2, (bf16_t*)(ws + OFF_WC2), 4, 8, g); return; }
  g -= G_WC2;
  if (g < G_WF1) { pack_frag8(Wf1, (bf16_t*)(ws + OFF_WF1), 8, 8, g); return; }
  g -= G_WF1;
  if (g < G_WC3) { pack_frag8(Wc3, (bf16_t*)(ws + OFF_WC3), 1, 2, g); return; }
  g -= G_WC3;
  if (g < G_WF2) { pack_frag8(Wf2, (bf16_t*)(ws + OFF_WF2), 2, 4, g); return; }
}

// ---------------- K1 body ----------------
__device__ __forceinline__ void k1_body(
    char* smem, int bid,
    const float* __restrict__ data, const float* __restrict__ proto, const float* __restrict__ var,
    const float* __restrict__ bf1g, const float* __restrict__ bf2g,
    const float* __restrict__ Wf3g, const float* __restrict__ bf3g,
    const bf16_t* __restrict__ Wf1p, const bf16_t* __restrict__ Wf2p,
    float* __restrict__ fsini)
{
  char* fs_lds   = smem;
  bf16_t* h2t    = (bf16_t*)(smem + 32768);
  float* proto_s = (float*)(smem + 36864);
  float* ivar_s  = (float*)(smem + 37888);

  const int r   = bid >> 8;
  const int b0  = (bid & 255) << 6;
  const int tid = threadIdx.x;
  const int lane = tid & 63;
  const int w   = tid >> 6;

  if (tid < FN) {
    proto_s[tid] = proto[r * FN + tid];
    float v = var[r * FN + tid];
    v = fminf(fmaxf(v, 1e-4f), 0.1f);
    ivar_s[tid] = 1.4426950408889634f * 0.5f / (v * v);
  }
  __syncthreads();

  { // membership
    const int row = tid >> 3;
    const int f0  = (tid & 7) << 5;
    const float* dp = data + (long)(b0 + row) * FN + f0;
    char* mrow = fs_lds + row * 512;
    const int sw = (row & 7) << 4;
    #pragma unroll
    for (int i = 0; i < 4; ++i) {
      const int f = f0 + i * 8;
      float4 x0 = *(const float4*)(dp + i * 8);
      float4 x1 = *(const float4*)(dp + i * 8 + 4);
      bf16x8 m; float d;
      d = x0.x - proto_s[f + 0]; m[0] = (bf16_t)__builtin_amdgcn_exp2f(-d * d * ivar_s[f + 0]);
      d = x0.y - proto_s[f + 1]; m[1] = (bf16_t)__builtin_amdgcn_exp2f(-d * d * ivar_s[f + 1]);
      d = x0.z - proto_s[f + 2]; m[2] = (bf16_t)__builtin_amdgcn_exp2f(-d * d * ivar_s[f + 2]);
      d = x0.w - proto_s[f + 3]; m[3] = (bf16_t)__builtin_amdgcn_exp2f(-d * d * ivar_s[f + 3]);
      d = x1.x - proto_s[f + 4]; m[4] = (bf16_t)__builtin_amdgcn_exp2f(-d * d * ivar_s[f + 4]);
      d = x1.y - proto_s[f + 5]; m[5] = (bf16_t)__builtin_amdgcn_exp2f(-d * d * ivar_s[f + 5]);
      d = x1.z - proto_s[f + 6]; m[6] = (bf16_t)__builtin_amdgcn_exp2f(-d * d * ivar_s[f + 6]);
      d = x1.w - proto_s[f + 7]; m[7] = (bf16_t)__builtin_amdgcn_exp2f(-d * d * ivar_s[f + 7]);
      *(bf16x8*)(mrow + ((f * 2) ^ sw)) = m;
    }
  }
  __syncthreads();

  // GEMM1: h1T = Wf1 @ memT, 2-deep reg double-buffer pipeline
  const int mg = w >> 1;
  const int ng = w & 1;
  f32x4 acc[2][2] = {};
  {
    bf16x8 aA[2], aB[2], bA[2], bB[2];
    #pragma unroll
    for (int i = 0; i < 2; ++i)
      aA[i] = *(const bf16x8*)(Wf1p + (((0 * 8 + mg * 2 + i) * 64 + lane)) * 8);
    #pragma unroll
    for (int j = 0; j < 2; ++j)
      bA[j] = lfrag(fs_lds, 512, (ng * 2 + j) * 16, 0, lane);
    #pragma unroll
    for (int ks = 0; ks < 8; ks += 2) {
      #pragma unroll
      for (int i = 0; i < 2; ++i)
        aB[i] = *(const bf16x8*)(Wf1p + ((((ks + 1) * 8 + mg * 2 + i) * 64 + lane)) * 8);
      #pragma unroll
      for (int j = 0; j < 2; ++j)
        bB[j] = lfrag(fs_lds, 512, (ng * 2 + j) * 16, (ks + 1) * 32, lane);
      #pragma unroll
      for (int i = 0; i < 2; ++i)
        #pragma unroll
        for (int j = 0; j < 2; ++j)
          acc[i][j] = mfma16(aA[i], bA[j], acc[i][j]);
      if (ks + 2 < 8) {
        #pragma unroll
        for (int i = 0; i < 2; ++i)
          aA[i] = *(const bf16x8*)(Wf1p + ((((ks + 2) * 8 + mg * 2 + i) * 64 + lane)) * 8);
        #pragma unroll
        for (int j = 0; j < 2; ++j)
          bA[j] = lfrag(fs_lds, 512, (ng * 2 + j) * 16, (ks + 2) * 32, lane);
      }
      #pragma unroll
      for (int i = 0; i < 2; ++i)
        #pragma unroll
        for (int j = 0; j < 2; ++j)
          acc[i][j] = mfma16(aB[i], bB[j], acc[i][j]);
    }
  }
  __syncthreads();   // mem reads done — overlay h1T in [0,16384)

  #pragma unroll
  for (int i = 0; i < 2; ++i) {
    const int hb = (mg * 2 + i) * 16 + ((lane >> 4) << 2);
    f32x4 bias = *(const f32x4*)(bf1g + hb);
    #pragma unroll
    for (int j = 0; j < 2; ++j) {
      const int b = (ng * 2 + j) * 16 + (lane & 15);
      bf16x4 o;
      #pragma unroll
      for (int q = 0; q < 4; ++q)
        o[q] = (bf16_t)fmaxf(acc[i][j][q] + bias[q], 0.f);
      *(bf16x4*)(fs_lds + b * 256 + ((hb * 2) ^ ((b & 7) << 4))) = o;
    }
  }
  __syncthreads();

  // GEMM2: h2T = Wf2 @ h1T
  {
    const int m = w >> 2;
    const int n = w & 3;
    f32x4 acc2 = {};
    #pragma unroll
    for (int ks = 0; ks < 4; ++ks) {
      bf16x8 a = *(const bf16x8*)(Wf2p + (((ks * 2 + m) * 64 + lane)) * 8);
      bf16x8 bb = lfrag(fs_lds, 256, n * 16, ks * 32, lane);
      acc2 = mfma16(a, bb, acc2);
    }
    const int p0 = m * 16 + ((lane >> 4) << 2);
    const int b  = n * 16 + (lane & 15);
    f32x4 bias = *(const f32x4*)(bf2g + p0);
    #pragma unroll
    for (int q = 0; q < 4; ++q)
      h2t[(p0 + q) * 64 + b] = (bf16_t)fmaxf(acc2[q] + bias[q], 0.f);
  }
  __syncthreads();

  if (tid < 64) {
    float s = bf3g[0];
    #pragma unroll
    for (int p = 0; p < H2N; ++p) s += (float)h2t[p * 64 + tid] * Wf3g[p];
    fsini[(long)(b0 + tid) * RN + r] = fmaxf(s, 0.f);
  }
}

// ---------------- K3 body ----------------
__device__ __forceinline__ void k3_body(
    char* smem, int bid,
    const bf16_t* __restrict__ datab,
    const bf16_t* __restrict__ Wc1p, const bf16_t* __restrict__ Wc2p, const bf16_t* __restrict__ Wc3p,
    const float* __restrict__ bc1, const float* __restrict__ bc2, const float* __restrict__ bc3,
    float* __restrict__ c3buf)
{
  char* a_lds  = smem;
  char* c2_lds = smem + 32768;

  const int xcd = bid & 7;
  const int kk  = bid >> 3;
  const int r   = xcd * 4 + (kk >> 8);
  const int b0  = (kk & 255) << 6;

  const int tid = threadIdx.x;
  const int lane = tid & 63;
  const int w   = tid >> 6;

  { // stage data tile
    const int row = tid >> 3;
    const int e0  = (tid & 7) << 5;
    const bf16_t* sp = datab + (long)(b0 + row) * FN + e0;
    char* drow = a_lds + row * 512;
    const int sw = (row & 7) << 4;
    #pragma unroll
    for (int i = 0; i < 4; ++i) {
      bf16x8 v = *(const bf16x8*)(sp + i * 8);
      *(bf16x8*)(drow + (((e0 + i * 8) * 2) ^ sw)) = v;
    }
  }
  __syncthreads();

  // GEMM1: c1T = Wc1 @ dataT, 2-deep reg double-buffer pipeline
  const int wm = w >> 1;
  const int wn = w & 1;
  const bf16_t* W1 = Wc1p + (long)r * G1N * FN;
  f32x4 acc[4][2] = {};
  {
    bf16x8 aA[4], aB[4], bA[2], bB[2];
    #pragma unroll
    for (int i = 0; i < 4; ++i)
      aA[i] = *(const bf16x8*)(W1 + (((0 * 16 + wm * 4 + i) * 64 + lane)) * 8);
    #pragma unroll
    for (int j = 0; j < 2; ++j)
      bA[j] = lfrag(a_lds, 512, (wn * 2 + j) * 16, 0, lane);
    #pragma unroll
    for (int ks = 0; ks < 8; ks += 2) {
      #pragma unroll
      for (int i = 0; i < 4; ++i)
        aB[i] = *(const bf16x8*)(W1 + ((((ks + 1) * 16 + wm * 4 + i) * 64 + lane)) * 8);
      #pragma unroll
      for (int j = 0; j < 2; ++j)
        bB[j] = lfrag(a_lds, 512, (wn * 2 + j) * 16, (ks + 1) * 32, lane);
      #pragma unroll
      for (int i = 0; i < 4; ++i)
        #pragma unroll
        for (int j = 0; j < 2; ++j)
          acc[i][j] = mfma16(aA[i], bA[j], acc[i][j]);
      if (ks + 2 < 8) {
        #pragma unroll
        for (int i = 0; i < 4; ++i)
          aA[i] = *(const bf16x8*)(W1 + ((((ks + 2) * 16 + wm * 4 + i) * 64 + lane)) * 8);
        #pragma unroll
        for (int j = 0; j < 2; ++j)
          bA[j] = lfrag(a_lds, 512, (wn * 2 + j) * 16, (ks + 2) * 32, lane);
      }
      #pragma unroll
      for (int i = 0; i < 4; ++i)
        #pragma unroll
        for (int j = 0; j < 2; ++j)
          acc[i][j] = mfma16(aB[i], bB[j], acc[i][j]);
    }
  }
  __syncthreads();  // data tile dead

  // c1T epilogue
  #pragma unroll
  for (int i = 0; i < 4; ++i) {
    const int g1b = (wm * 4 + i) * 16 + ((lane >> 4) << 2);
    f32x4 bias = *(const f32x4*)(bc1 + r * G1N + g1b);
    #pragma unroll
    for (int j = 0; j < 2; ++j) {
      const int b = (wn * 2 + j) * 16 + (lane & 15);
      bf16x4 o;
      #pragma unroll
      for (int q = 0; q < 4; ++q)
        o[q] = (bf16_t)elu_f(acc[i][j][q] + bias[q]);
      *(bf16x4*)(a_lds + b * 512 + ((g1b * 2) ^ ((b & 7) << 4))) = o;
    }
  }
  __syncthreads();

  // GEMM2: c2T = Wc2 @ c1T, 2-deep pipeline
  const int m2 = w >> 1;
  const int n2 = w & 1;
  const bf16_t* W2 = Wc2p + (long)r * G2N * G1N;
  f32x4 acc2[2] = {};
  {
    bf16x8 a2A, a2B, b2A[2], b2B[2];
    a2A = *(const bf16x8*)(W2 + (((0 * 4 + m2) * 64 + lane)) * 8);
    #pragma unroll
    for (int j = 0; j < 2; ++j)
      b2A[j] = lfrag(a_lds, 512, (n2 * 2 + j) * 16, 0, lane);
    #pragma unroll
    for (int ks = 0; ks < 8; ks += 2) {
      a2B = *(const bf16x8*)(W2 + ((((ks + 1) * 4 + m2) * 64 + lane)) * 8);
      #pragma unroll
      for (int j = 0; j < 2; ++j)
        b2B[j] = lfrag(a_lds, 512, (n2 * 2 + j) * 16, (ks + 1) * 32, lane);
      #pragma unroll
      for (int j = 0; j < 2; ++j)
        acc2[j] = mfma16(a2A, b2A[j], acc2[j]);
      if (ks + 2 < 8) {
        a2A = *(const bf16x8*)(W2 + ((((ks + 2) * 4 + m2) * 64 + lane)) * 8);
        #pragma unroll
        for (int j = 0; j < 2; ++j)
          b2A[j] = lfrag(a_lds, 512, (n2 * 2 + j) * 16, (ks + 2) * 32, lane);
      }
      #pragma unroll
      for (int j = 0; j < 2; ++j)
        acc2[j] = mfma16(a2B, b2B[j], acc2[j]);
    }
  }
  {
    const int g2b = m2 * 16 + ((lane >> 4) << 2);
    f32x4 bias = *(const f32x4*)(bc2 + r * G2N + g2b);
    #pragma unroll
    for (int j = 0; j < 2; ++j) {
      const int b = (n2 * 2 + j) * 16 + (lane & 15);
      bf16x4 o;
      #pragma unroll
      for (int q = 0; q < 4; ++q)
        o[q] = (bf16_t)elu_f(acc2[j][q] + bias[q]);
      *(bf16x4*)(c2_lds + b * 128 + ((g2b * 2) ^ ((b & 7) << 4))) = o;
    }
  }
  __syncthreads();

  // GEMM3
  if (w < 4) {
    const bf16_t* W3 = Wc3p + (long)r * CN * G2N;
    f32x4 acc3 = {};
    #pragma unroll
    for (int ks = 0; ks < 2; ++ks) {
      bf16x8 a = *(const bf16x8*)(W3 + (((long)ks * 64 + lane)) * 8);
      bf16x8 bb = lfrag(c2_lds, 128, w * 16, ks * 32, lane);
      acc3 = mfma16(a, bb, acc3);
    }
    const int c0 = ((lane >> 4) << 2);
    const int b  = w * 16 + (lane & 15);
    f32x4 bias = *(const f32x4*)(bc3 + r * CN + c0);
    f32x4 o;
    #pragma unroll
    for (int q = 0; q < 4; ++q) o[q] = fmaxf(acc3[q] + bias[q], 0.f);
    *(f32x4*)(c3buf + ((long)r * BN + b0 + b) * CN + c0) = o;
  }
}

// Fused, XCD-aware interleave. HW maps block -> XCD as (bid % 8), so the path
// selector must NOT be bid parity (that segregates K1/K3 onto disjoint XCDs).
// Use groups of 8: sel = (bid>>3)&1, local = ((bid>>4)<<3)|(bid&7).
// Every XCD then hosts both K1 and K3 blocks, and local%8 == physical XCD,
// preserving k3_body's weight-locality swizzle.
__global__ __launch_bounds__(512, 6) void k13_fused(
    const float* __restrict__ data, const float* __restrict__ proto, const float* __restrict__ var,
    const float* __restrict__ bf1g, const float* __restrict__ bf2g,
    const float* __restrict__ Wf3g, const float* __restrict__ bf3g,
    const bf16_t* __restrict__ Wf1p, const bf16_t* __restrict__ Wf2p,
    float* __restrict__ fsini,
    const bf16_t* __restrict__ datab,
    const bf16_t* __restrict__ Wc1p, const bf16_t* __restrict__ Wc2p, const bf16_t* __restrict__ Wc3p,
    const float* __restrict__ bc1, const float* __restrict__ bc2, const float* __restrict__ bc3,
    float* __restrict__ c3buf)
{
  __shared__ __attribute__((aligned(16))) char smem[40960];
  const int bid   = blockIdx.x;
  const int sel   = (bid >> 3) & 1;
  const int local = ((bid >> 4) << 3) | (bid & 7);
  if (sel) {
    k1_body(smem, local, data, proto, var, bf1g, bf2g, Wf3g, bf3g, Wf1p, Wf2p, fsini);
  } else {
    k3_body(smem, local, datab, Wc1p, Wc2p, Wc3p, bc1, bc2, bc3, c3buf);
  }
}

__global__ __launch_bounds__(256) void k2_softmax(const float* __restrict__ fsini,
                                                  float* __restrict__ fire)
{
  int b = blockIdx.x * 256 + threadIdx.x;
  float v[RN];
  const float4* p = (const float4*)(fsini + (long)b * RN);
  #pragma unroll
  for (int i = 0; i < RN / 4; ++i) {
    float4 t = p[i];
    v[4 * i] = t.x; v[4 * i + 1] = t.y; v[4 * i + 2] = t.z; v[4 * i + 3] = t.w;
  }
  float m = v[0];
  #pragma unroll
  for (int i = 1; i < RN; ++i) m = fmaxf(m, v[i]);
  float s = 0.f;
  #pragma unroll
  for (int i = 0; i < RN; ++i) { v[i] = expf(v[i] - m); s += v[i]; }
  float inv = 1.f / s;
  float4* o = (float4*)(fire + (long)b * RN);
  #pragma unroll
  for (int i = 0; i < RN / 4; ++i) {
    float4 t; t.x = v[4 * i] * inv; t.y = v[4 * i + 1] * inv;
    t.z = v[4 * i + 2] * inv; t.w = v[4 * i + 3] * inv;
    o[i] = t;
  }
}

__global__ __launch_bounds__(256) void k4_out(const float* __restrict__ c3buf,
                                              const float* __restrict__ fire,
                                              float* __restrict__ out)
{
  int t = blockIdx.x * 256 + threadIdx.x;
  int b = t >> 2, c4 = (t & 3) << 2;
  const float* fp = fire + (long)b * RN;
  f32x4 s = {};
  #pragma unroll
  for (int rr = 0; rr < RN; ++rr) {
    float fw = fp[rr];
    f32x4 v = *(const f32x4*)(c3buf + ((long)rr * BN + b) * CN + c4);
    s += fw * v;
  }
  *(f32x4*)(out + (long)b * CN + c4) = s;
}

extern "C" void kernel_launch(void* const* d_in, const int* in_sizes, int n_in,
                              void* d_out, int out_size, void* d_ws, size_t ws_size,
                              hipStream_t stream) {
  const float* data = (const float*)d_in[0];
  const float* proto = (const float*)d_in[1];
  const float* var  = (const float*)d_in[2];
  const float* Wf1  = (const float*)d_in[3];
  const float* bf1  = (const float*)d_in[4];
  const float* Wf2  = (const float*)d_in[5];
  const float* bf2  = (const float*)d_in[6];
  const float* Wf3  = (const float*)d_in[7];
  const float* bf3  = (const float*)d_in[8];
  const float* Wc1  = (const float*)d_in[9];
  const float* bc1  = (const float*)d_in[10];
  const float* Wc2  = (const float*)d_in[11];
  const float* bc2  = (const float*)d_in[12];
  const float* Wc3  = (const float*)d_in[13];
  const float* bc3  = (const float*)d_in[14];

  char* ws = (char*)d_ws;
  bf16_t* datab = (bf16_t*)(ws + OFF_DATA);
  bf16_t* Wf1p  = (bf16_t*)(ws + OFF_WF1);
  bf16_t* Wf2p  = (bf16_t*)(ws + OFF_WF2);
  bf16_t* Wc1p  = (bf16_t*)(ws + OFF_WC1);
  bf16_t* Wc2p  = (bf16_t*)(ws + OFF_WC2);
  bf16_t* Wc3p  = (bf16_t*)(ws + OFF_WC3);
  float*  fsini = (float*)(ws + OFF_FSINI);
  float*  c3buf = (float*)(ws + OFF_C3);

  float* out  = (float*)d_out;               // [B][C]
  float* fire = out + (long)BN * CN;         // [B][R]

  k0_pack<<<G_TOTAL / 256, 256, 0, stream>>>(data, Wf1, Wf2, Wc1, Wc2, Wc3, ws);
  k13_fused<<<2 * RN * (BN / 64), 512, 0, stream>>>(
      data, proto, var, bf1, bf2, Wf3, bf3, Wf1p, Wf2p, fsini,
      datab, Wc1p, Wc2p, Wc3p, bc1, bc2, bc3, c3buf);
  k2_softmax<<<BN / 256, 256, 0, stream>>>(fsini, fire);
  k4_out<<<(BN * CN / 4) / 256, 256, 0, stream>>>(c3buf, fire, out);
}

// Round 11
// 251.034 us; speedup vs baseline: 1.0353x; 1.0353x over previous
//
#include <hip/hip_runtime.h>
#include <hip/hip_bf16.h>

// Problem dims
#define BN 16384
#define FN 256
#define RN 32
#define CN 16
#define H1N 128
#define H2N 32
#define G1N 256
#define G2N 64

typedef __bf16 bf16_t;
typedef __bf16 bf16x8 __attribute__((ext_vector_type(8)));
typedef __bf16 bf16x4 __attribute__((ext_vector_type(4)));
typedef float f32x4 __attribute__((ext_vector_type(4)));

// ---- workspace byte offsets (all 16B-aligned) ----
#define OFF_DATA   0UL
#define OFF_WF1    8388608UL
#define OFF_WF2    8454144UL
#define OFF_WC1    8462336UL
#define OFF_WC2    12656640UL
#define OFF_WC3    13705216UL
#define OFF_FSINI  13770752UL
#define OFF_C3     15867904UL

__device__ __forceinline__ f32x4 mfma16(bf16x8 a, bf16x8 b, f32x4 c) {
  return __builtin_amdgcn_mfma_f32_16x16x32_bf16(a, b, c, 0, 0, 0);
}

__device__ __forceinline__ float elu_f(float v) {
  float e = __builtin_amdgcn_exp2f(v * 1.44269504f) - 1.0f;
  return v > 0.f ? v : e;
}

__device__ __forceinline__ bf16x8 lfrag(const char* base, int strideB, int n0, int k0, int lane) {
  int row = n0 + (lane & 15);
  int off = (k0 * 2 + ((lane >> 4) << 4)) ^ ((row & 7) << 4);
  return *(const bf16x8*)(base + row * strideB + off);
}

__device__ __forceinline__ void pack_frag8(const float* __restrict__ src, bf16_t* __restrict__ dst,
                                           int NT, int KS, int g) {
  int per = NT * KS * 64;
  int r = g / per;
  int local = g - r * per;
  int lane = local & 63;
  int fr = local >> 6;
  int ks = fr / NT;
  int nt = fr - ks * NT;
  int N = NT * 16, K = KS * 32;
  int n = nt * 16 + (lane & 15);
  int k = ks * 32 + ((lane >> 4) << 3);
  const float* s = src + (long)r * N * K + (long)n * K + k;
  float4 a = *(const float4*)s;
  float4 b = *(const float4*)(s + 4);
  bf16x8 o;
  o[0] = (bf16_t)a.x; o[1] = (bf16_t)a.y; o[2] = (bf16_t)a.z; o[3] = (bf16_t)a.w;
  o[4] = (bf16_t)b.x; o[5] = (bf16_t)b.y; o[6] = (bf16_t)b.z; o[7] = (bf16_t)b.w;
  *(bf16x8*)(dst + (long)g * 8) = o;
}

#define G_DATA 524288
#define G_WC1  262144
#define G_WC2  65536
#define G_WF1  4096
#define G_WC3  4096
#define G_WF2  512
#define G_TOTAL (G_DATA + G_WC1 + G_WC2 + G_WF1 + G_WC3 + G_WF2)

__global__ __launch_bounds__(256) void k0_pack(
    const float* __restrict__ data, const float* __restrict__ Wf1, const float* __restrict__ Wf2,
    const float* __restrict__ Wc1, const float* __restrict__ Wc2, const float* __restrict__ Wc3,
    char* __restrict__ ws)
{
  int g = blockIdx.x * 256 + threadIdx.x;
  if (g < G_DATA) {
    const float* s = data + (long)g * 8;
    float4 a = *(const float4*)s, b = *(const float4*)(s + 4);
    bf16x8 o;
    o[0] = (bf16_t)a.x; o[1] = (bf16_t)a.y; o[2] = (bf16_t)a.z; o[3] = (bf16_t)a.w;
    o[4] = (bf16_t)b.x; o[5] = (bf16_t)b.y; o[6] = (bf16_t)b.z; o[7] = (bf16_t)b.w;
    *(bf16x8*)((bf16_t*)(ws + OFF_DATA) + (long)g * 8) = o;
    return;
  }
  g -= G_DATA;
  if (g < G_WC1) { pack_frag8(Wc1, (bf16_t*)(ws + OFF_WC1), 16, 8, g); return; }
  g -= G_WC1;
  if (g < G_WC2) { pack_frag8(Wc2, (bf16_t*)(ws + OFF_WC2), 4, 8, g); return; }
  g -= G_WC2;
  if (g < G_WF1) { pack_frag8(Wf1, (bf16_t*)(ws + OFF_WF1), 8, 8, g); return; }
  g -= G_WF1;
  if (g < G_WC3) { pack_frag8(Wc3, (bf16_t*)(ws + OFF_WC3), 1, 2, g); return; }
  g -= G_WC3;
  if (g < G_WF2) { pack_frag8(Wf2, (bf16_t*)(ws + OFF_WF2), 2, 4, g); return; }
}

// ---------------- K1 body: FS chain, per (rule, 64-row tile) ----------------
// GEMM1 wave layout deduped: wave w owns m-tile w (16 h-rows), ALL 4 n-tiles.
// Wf1 global traffic per block: 64KB (was 128KB, 2x dup).
__device__ __forceinline__ void k1_body(
    char* smem, int bid,
    const float* __restrict__ data, const float* __restrict__ proto, const float* __restrict__ var,
    const float* __restrict__ bf1g, const float* __restrict__ bf2g,
    const float* __restrict__ Wf3g, const float* __restrict__ bf3g,
    const bf16_t* __restrict__ Wf1p, const bf16_t* __restrict__ Wf2p,
    float* __restrict__ fsini)
{
  char* fs_lds   = smem;
  bf16_t* h2t    = (bf16_t*)(smem + 32768);
  float* proto_s = (float*)(smem + 36864);
  float* ivar_s  = (float*)(smem + 37888);

  const int r   = bid >> 8;
  const int b0  = (bid & 255) << 6;
  const int tid = threadIdx.x;
  const int lane = tid & 63;
  const int w   = tid >> 6;

  if (tid < FN) {
    proto_s[tid] = proto[r * FN + tid];
    float v = var[r * FN + tid];
    v = fminf(fmaxf(v, 1e-4f), 0.1f);
    ivar_s[tid] = 1.4426950408889634f * 0.5f / (v * v);
  }
  __syncthreads();

  { // membership
    const int row = tid >> 3;
    const int f0  = (tid & 7) << 5;
    const float* dp = data + (long)(b0 + row) * FN + f0;
    char* mrow = fs_lds + row * 512;
    const int sw = (row & 7) << 4;
    #pragma unroll
    for (int i = 0; i < 4; ++i) {
      const int f = f0 + i * 8;
      float4 x0 = *(const float4*)(dp + i * 8);
      float4 x1 = *(const float4*)(dp + i * 8 + 4);
      bf16x8 m; float d;
      d = x0.x - proto_s[f + 0]; m[0] = (bf16_t)__builtin_amdgcn_exp2f(-d * d * ivar_s[f + 0]);
      d = x0.y - proto_s[f + 1]; m[1] = (bf16_t)__builtin_amdgcn_exp2f(-d * d * ivar_s[f + 1]);
      d = x0.z - proto_s[f + 2]; m[2] = (bf16_t)__builtin_amdgcn_exp2f(-d * d * ivar_s[f + 2]);
      d = x0.w - proto_s[f + 3]; m[3] = (bf16_t)__builtin_amdgcn_exp2f(-d * d * ivar_s[f + 3]);
      d = x1.x - proto_s[f + 4]; m[4] = (bf16_t)__builtin_amdgcn_exp2f(-d * d * ivar_s[f + 4]);
      d = x1.y - proto_s[f + 5]; m[5] = (bf16_t)__builtin_amdgcn_exp2f(-d * d * ivar_s[f + 5]);
      d = x1.z - proto_s[f + 6]; m[6] = (bf16_t)__builtin_amdgcn_exp2f(-d * d * ivar_s[f + 6]);
      d = x1.w - proto_s[f + 7]; m[7] = (bf16_t)__builtin_amdgcn_exp2f(-d * d * ivar_s[f + 7]);
      *(bf16x8*)(mrow + ((f * 2) ^ sw)) = m;
    }
  }
  __syncthreads();

  // GEMM1: h1T[h=128][b=64] = Wf1 @ memT. wave w -> m-tile w, n-tiles 0..3. No W-dup.
  f32x4 acc[4] = {};
  #pragma unroll
  for (int ks = 0; ks < 8; ++ks) {
    bf16x8 a = *(const bf16x8*)(Wf1p + (((ks * 8 + w) * 64 + lane)) * 8);
    #pragma unroll
    for (int j = 0; j < 4; ++j) {
      bf16x8 bb = lfrag(fs_lds, 512, j * 16, ks * 32, lane);
      acc[j] = mfma16(a, bb, acc[j]);
    }
  }
  __syncthreads();   // mem reads done — overlay h1T in [0,16384)

  {
    const int hb = w * 16 + ((lane >> 4) << 2);   // 4 consecutive h rows
    f32x4 bias = *(const f32x4*)(bf1g + hb);
    #pragma unroll
    for (int j = 0; j < 4; ++j) {
      const int b = j * 16 + (lane & 15);
      bf16x4 o;
      #pragma unroll
      for (int q = 0; q < 4; ++q)
        o[q] = (bf16_t)fmaxf(acc[j][q] + bias[q], 0.f);
      *(bf16x4*)(fs_lds + b * 256 + ((hb * 2) ^ ((b & 7) << 4))) = o;
    }
  }
  __syncthreads();

  // GEMM2: h2T[p=32][b=64] = Wf2 @ h1T. 2 m x 4 n = 8 tiles, 1/wave
  {
    const int m = w >> 2;
    const int n = w & 3;
    f32x4 acc2 = {};
    #pragma unroll
    for (int ks = 0; ks < 4; ++ks) {
      bf16x8 a = *(const bf16x8*)(Wf2p + (((ks * 2 + m) * 64 + lane)) * 8);
      bf16x8 bb = lfrag(fs_lds, 256, n * 16, ks * 32, lane);
      acc2 = mfma16(a, bb, acc2);
    }
    const int p0 = m * 16 + ((lane >> 4) << 2);
    const int b  = n * 16 + (lane & 15);
    f32x4 bias = *(const f32x4*)(bf2g + p0);
    #pragma unroll
    for (int q = 0; q < 4; ++q)
      h2t[(p0 + q) * 64 + b] = (bf16_t)fmaxf(acc2[q] + bias[q], 0.f);
  }
  __syncthreads();

  if (tid < 64) {
    float s = bf3g[0];
    #pragma unroll
    for (int p = 0; p < H2N; ++p) s += (float)h2t[p * 64 + tid] * Wf3g[p];
    fsini[(long)(b0 + tid) * RN + r] = fmaxf(s, 0.f);
  }
}

// ---------------- K3 body: consequent chain, per (rule, 64-row tile) ----------------
// GEMM1 wave layout deduped: wave w owns m-tiles {2w,2w+1} (32 g1-rows), ALL 4 n-tiles.
// Wc1 global traffic per block: 128KB (was 256KB, 2x dup).
__device__ __forceinline__ void k3_body(
    char* smem, int bid,
    const bf16_t* __restrict__ datab,
    const bf16_t* __restrict__ Wc1p, const bf16_t* __restrict__ Wc2p, const bf16_t* __restrict__ Wc3p,
    const float* __restrict__ bc1, const float* __restrict__ bc2, const float* __restrict__ bc3,
    float* __restrict__ c3buf)
{
  char* a_lds  = smem;
  char* c2_lds = smem + 32768;

  const int xcd = bid & 7;
  const int kk  = bid >> 3;
  const int r   = xcd * 4 + (kk >> 8);
  const int b0  = (kk & 255) << 6;

  const int tid = threadIdx.x;
  const int lane = tid & 63;
  const int w   = tid >> 6;

  { // stage data tile
    const int row = tid >> 3;
    const int e0  = (tid & 7) << 5;
    const bf16_t* sp = datab + (long)(b0 + row) * FN + e0;
    char* drow = a_lds + row * 512;
    const int sw = (row & 7) << 4;
    #pragma unroll
    for (int i = 0; i < 4; ++i) {
      bf16x8 v = *(const bf16x8*)(sp + i * 8);
      *(bf16x8*)(drow + (((e0 + i * 8) * 2) ^ sw)) = v;
    }
  }
  __syncthreads();

  // GEMM1: c1T[g1=256][b=64]. wave w -> m-tiles {2w,2w+1}, n-tiles 0..3. No W-dup.
  const bf16_t* W1 = Wc1p + (long)r * G1N * FN;
  f32x4 acc[2][4] = {};
  #pragma unroll
  for (int ks = 0; ks < 8; ++ks) {
    bf16x8 a[2], bb[4];
    #pragma unroll
    for (int i = 0; i < 2; ++i)
      a[i] = *(const bf16x8*)(W1 + (((ks * 16 + w * 2 + i) * 64 + lane)) * 8);
    #pragma unroll
    for (int j = 0; j < 4; ++j)
      bb[j] = lfrag(a_lds, 512, j * 16, ks * 32, lane);
    #pragma unroll
    for (int i = 0; i < 2; ++i)
      #pragma unroll
      for (int j = 0; j < 4; ++j)
        acc[i][j] = mfma16(a[i], bb[j], acc[i][j]);
  }
  __syncthreads();  // data tile dead

  // c1T epilogue: elu -> bf16 [b][g1] overlay
  #pragma unroll
  for (int i = 0; i < 2; ++i) {
    const int g1b = (w * 2 + i) * 16 + ((lane >> 4) << 2);
    f32x4 bias = *(const f32x4*)(bc1 + r * G1N + g1b);
    #pragma unroll
    for (int j = 0; j < 4; ++j) {
      const int b = j * 16 + (lane & 15);
      bf16x4 o;
      #pragma unroll
      for (int q = 0; q < 4; ++q)
        o[q] = (bf16_t)elu_f(acc[i][j][q] + bias[q]);
      *(bf16x4*)(a_lds + b * 512 + ((g1b * 2) ^ ((b & 7) << 4))) = o;
    }
  }
  __syncthreads();

  // GEMM2: c2T[g2=64][b=64]. 4 m x 4 n = 16 tiles; wave: 1m x 2n
  const int m2 = w >> 1;
  const int n2 = w & 1;
  const bf16_t* W2 = Wc2p + (long)r * G2N * G1N;
  f32x4 acc2[2] = {};
  #pragma unroll
  for (int ks = 0; ks < 8; ++ks) {
    bf16x8 a = *(const bf16x8*)(W2 + (((ks * 4 + m2) * 64 + lane)) * 8);
    #pragma unroll
    for (int j = 0; j < 2; ++j) {
      bf16x8 bb = lfrag(a_lds, 512, (n2 * 2 + j) * 16, ks * 32, lane);
      acc2[j] = mfma16(a, bb, acc2[j]);
    }
  }
  {
    const int g2b = m2 * 16 + ((lane >> 4) << 2);
    f32x4 bias = *(const f32x4*)(bc2 + r * G2N + g2b);
    #pragma unroll
    for (int j = 0; j < 2; ++j) {
      const int b = (n2 * 2 + j) * 16 + (lane & 15);
      bf16x4 o;
      #pragma unroll
      for (int q = 0; q < 4; ++q)
        o[q] = (bf16_t)elu_f(acc2[j][q] + bias[q]);
      *(bf16x4*)(c2_lds + b * 128 + ((g2b * 2) ^ ((b & 7) << 4))) = o;
    }
  }
  __syncthreads();

  // GEMM3
  if (w < 4) {
    const bf16_t* W3 = Wc3p + (long)r * CN * G2N;
    f32x4 acc3 = {};
    #pragma unroll
    for (int ks = 0; ks < 2; ++ks) {
      bf16x8 a = *(const bf16x8*)(W3 + (((long)ks * 64 + lane)) * 8);
      bf16x8 bb = lfrag(c2_lds, 128, w * 16, ks * 32, lane);
      acc3 = mfma16(a, bb, acc3);
    }
    const int c0 = ((lane >> 4) << 2);
    const int b  = w * 16 + (lane & 15);
    f32x4 bias = *(const f32x4*)(bc3 + r * CN + c0);
    f32x4 o;
    #pragma unroll
    for (int q = 0; q < 4; ++q) o[q] = fmaxf(acc3[q] + bias[q], 0.f);
    *(f32x4*)(c3buf + ((long)r * BN + b0 + b) * CN + c0) = o;
  }
}

// Fused, parity interleave (R9 best): K3 on even bids, K1 on odd bids.
// Parity segregates the two paths onto disjoint XCD sets -> separate L2 working sets
// (measured better than co-residency, which thrashed L2: R10 FETCH +60%).
__global__ __launch_bounds__(512) void k13_fused(
    const float* __restrict__ data, const float* __restrict__ proto, const float* __restrict__ var,
    const float* __restrict__ bf1g, const float* __restrict__ bf2g,
    const float* __restrict__ Wf3g, const float* __restrict__ bf3g,
    const bf16_t* __restrict__ Wf1p, const bf16_t* __restrict__ Wf2p,
    float* __restrict__ fsini,
    const bf16_t* __restrict__ datab,
    const bf16_t* __restrict__ Wc1p, const bf16_t* __restrict__ Wc2p, const bf16_t* __restrict__ Wc3p,
    const float* __restrict__ bc1, const float* __restrict__ bc2, const float* __restrict__ bc3,
    float* __restrict__ c3buf)
{
  __shared__ __attribute__((aligned(16))) char smem[40960];
  const int bid = blockIdx.x;
  if (bid & 1) {
    k1_body(smem, bid >> 1, data, proto, var, bf1g, bf2g, Wf3g, bf3g, Wf1p, Wf2p, fsini);
  } else {
    k3_body(smem, bid >> 1, datab, Wc1p, Wc2p, Wc3p, bc1, bc2, bc3, c3buf);
  }
}

__global__ __launch_bounds__(256) void k2_softmax(const float* __restrict__ fsini,
                                                  float* __restrict__ fire)
{
  int b = blockIdx.x * 256 + threadIdx.x;
  float v[RN];
  const float4* p = (const float4*)(fsini + (long)b * RN);
  #pragma unroll
  for (int i = 0; i < RN / 4; ++i) {
    float4 t = p[i];
    v[4 * i] = t.x; v[4 * i + 1] = t.y; v[4 * i + 2] = t.z; v[4 * i + 3] = t.w;
  }
  float m = v[0];
  #pragma unroll
  for (int i = 1; i < RN; ++i) m = fmaxf(m, v[i]);
  float s = 0.f;
  #pragma unroll
  for (int i = 0; i < RN; ++i) { v[i] = expf(v[i] - m); s += v[i]; }
  float inv = 1.f / s;
  float4* o = (float4*)(fire + (long)b * RN);
  #pragma unroll
  for (int i = 0; i < RN / 4; ++i) {
    float4 t; t.x = v[4 * i] * inv; t.y = v[4 * i + 1] * inv;
    t.z = v[4 * i + 2] * inv; t.w = v[4 * i + 3] * inv;
    o[i] = t;
  }
}

__global__ __launch_bounds__(256) void k4_out(const float* __restrict__ c3buf,
                                              const float* __restrict__ fire,
                                              float* __restrict__ out)
{
  int t = blockIdx.x * 256 + threadIdx.x;
  int b = t >> 2, c4 = (t & 3) << 2;
  const float* fp = fire + (long)b * RN;
  f32x4 s = {};
  #pragma unroll
  for (int rr = 0; rr < RN; ++rr) {
    float fw = fp[rr];
    f32x4 v = *(const f32x4*)(c3buf + ((long)rr * BN + b) * CN + c4);
    s += fw * v;
  }
  *(f32x4*)(out + (long)b * CN + c4) = s;
}

extern "C" void kernel_launch(void* const* d_in, const int* in_sizes, int n_in,
                              void* d_out, int out_size, void* d_ws, size_t ws_size,
                              hipStream_t stream) {
  const float* data = (const float*)d_in[0];
  const float* proto = (const float*)d_in[1];
  const float* var  = (const float*)d_in[2];
  const float* Wf1  = (const float*)d_in[3];
  const float* bf1  = (const float*)d_in[4];
  const float* Wf2  = (const float*)d_in[5];
  const float* bf2  = (const float*)d_in[6];
  const float* Wf3  = (const float*)d_in[7];
  const float* bf3  = (const float*)d_in[8];
  const float* Wc1  = (const float*)d_in[9];
  const float* bc1  = (const float*)d_in[10];
  const float* Wc2  = (const float*)d_in[11];
  const float* bc2  = (const float*)d_in[12];
  const float* Wc3  = (const float*)d_in[13];
  const float* bc3  = (const float*)d_in[14];

  char* ws = (char*)d_ws;
  bf16_t* datab = (bf16_t*)(ws + OFF_DATA);
  bf16_t* Wf1p  = (bf16_t*)(ws + OFF_WF1);
  bf16_t* Wf2p  = (bf16_t*)(ws + OFF_WF2);
  bf16_t* Wc1p  = (bf16_t*)(ws + OFF_WC1);
  bf16_t* Wc2p  = (bf16_t*)(ws + OFF_WC2);
  bf16_t* Wc3p  = (bf16_t*)(ws + OFF_WC3);
  float*  fsini = (float*)(ws + OFF_FSINI);
  float*  c3buf = (float*)(ws + OFF_C3);

  float* out  = (float*)d_out;               // [B][C]
  float* fire = out + (long)BN * CN;         // [B][R]

  k0_pack<<<G_TOTAL / 256, 256, 0, stream>>>(data, Wf1, Wf2, Wc1, Wc2, Wc3, ws);
  k13_fused<<<2 * RN * (BN / 64), 512, 0, stream>>>(
      data, proto, var, bf1, bf2, Wf3, bf3, Wf1p, Wf2p, fsini,
      datab, Wc1p, Wc2p, Wc3p, bc1, bc2, bc3, c3buf);
  k2_softmax<<<BN / 256, 256, 0, stream>>>(fsini, fire);
  k4_out<<<(BN * CN / 4) / 256, 256, 0, stream>>>(c3buf, fire, out);
}